// Round 3
// baseline (148.985 us; speedup 1.0000x reference)
//
#include <hip/hip_runtime.h>

// out[m,n] = prod_d softplus(min(Zm,Ze)-max(zm,ze)) / softplus(Zm-zm)
//
// - product-of-ratios in log2 domain (ln2^64 cancels num/denom) -> inner unit
//   is min,min,fma(1+a*b),v_log_f32,mul. v_log is ~1/8 rate => it dominates.
// - e^{hi-lo} = min(e^Zm,e^Ze)*min(e^-zm,e^-ze); row exps staged in LDS.
// - d-SPLIT: stage 32 of 64 dims per phase -> LDS 26.2 KB -> 6 blocks/CU
//   capacity; accumulator p persists across phases.
// - balanced persistent grid: 157x8 blocks, each does exactly 2 n-tiles
//   (j and j+157) -> ~4.9 blocks/CU all co-resident, no 81%-fill tail.
// - conflict-free staging: NST=66 (stride 2 mod 32 -> transpose writes 2-way
//   = free), men writes 2-way free; float2 LDS reads stay 8B-aligned.
// - per-8-d-chunk denominator reciprocal sRc (underflow-safe: chunk prod
//   >= (1.8e-4)^8 = 1e-30, rc <= 1e30 finite; flushed outputs << 8e-13 thr).

#define BM 32
#define BN 64
#define DH 32            // dims staged per phase
#define MST 34           // stride  2 mod 32: 2-way banks (free), 8B align
#define NST 66           // stride  2 mod 32: 2-way banks (free), 8B align

__global__ __launch_bounds__(256, 5)
void ivr_kernel(const float* __restrict__ men, const float* __restrict__ en,
                float* __restrict__ out, int M, int N, int ntl, int jst) {
    __shared__ float sEm[DH][MST];   // e^{Zm}   [d][m]
    __shared__ float sIm[DH][MST];   // e^{-zm}
    __shared__ float sEe[DH][NST];   // e^{Ze}   [d][n]
    __shared__ float sIe[DH][NST];   // e^{-ze}
    __shared__ float sRc[4][MST];    // 1/prod_{chunk} log2(1+e^{Zm-zm})

    const int tx = threadIdx.x;
    const int m0 = blockIdx.y * BM;
    const int j  = blockIdx.x;

    const int ni = (tx & 15) * 4;    // 16 n-groups of 4
    const int mi = (tx >> 4) * 2;    // 16 m-groups of 2

    const int ntiles = (j + jst < ntl) ? 2 : 1;

    for (int t = 0; t < ntiles; ++t) {
        const int n0 = (j + t * jst) * BN;

        float p[2][4];
        #pragma unroll
        for (int i = 0; i < 2; ++i)
            #pragma unroll
            for (int jj = 0; jj < 4; ++jj) p[i][jj] = 1.0f;

        #pragma unroll
        for (int h = 0; h < 2; ++h) {
            const int dofs = h * DH;

            // ---- men staging: threads 0..127 -> (m = tx&31, chunk c = tx>>5) ----
            if (tx < 128) {
                const int m = tx & 31;
                const int c = tx >> 5;                 // 0..3, 8 d's each
                int mm = m0 + m; if (mm >= M) mm = M - 1;
                const float* row = men + (size_t)mm * 128 + dofs + c * 8;
                const float4 za = *reinterpret_cast<const float4*>(row);
                const float4 zb = *reinterpret_cast<const float4*>(row + 4);
                const float4 Za = *reinterpret_cast<const float4*>(row + 64);
                const float4 Zb = *reinterpret_cast<const float4*>(row + 68);
                const float zA[8] = {za.x, za.y, za.z, za.w, zb.x, zb.y, zb.z, zb.w};
                const float ZA[8] = {Za.x, Za.y, Za.z, Za.w, Zb.x, Zb.y, Zb.z, Zb.w};
                float prod = 1.0f;
                #pragma unroll
                for (int k = 0; k < 8; ++k) {
                    const int dl = c * 8 + k;
                    const float Em = __expf(ZA[k]);
                    const float Im = __expf(-zA[k]);
                    sEm[dl][m] = Em;                   // bank (2dl+m)%32: 2-way free
                    sIm[dl][m] = Im;
                    prod *= __log2f(fmaf(Em, Im, 1.0f));
                }
                sRc[c][m] = 1.0f / prod;
            }
            // ---- entity staging: all threads, float4 global reads ----
            #pragma unroll
            for (int it = 0; it < 2; ++it) {
                const int q   = tx + it * 256;         // 512 quads = 64n x 32d
                const int dl4 = (q & 7) * 4;
                const int n   = q >> 3;
                int nn = n0 + n; if (nn >= N) nn = N - 1;
                const float* erow = en + (size_t)nn * 128 + dofs + dl4;
                const float4 z4 = *reinterpret_cast<const float4*>(erow);
                const float4 Z4 = *reinterpret_cast<const float4*>(erow + 64);
                sEe[dl4 + 0][n] = __expf(Z4.x);        // bank (2d+n)%32: 2-way free
                sEe[dl4 + 1][n] = __expf(Z4.y);
                sEe[dl4 + 2][n] = __expf(Z4.z);
                sEe[dl4 + 3][n] = __expf(Z4.w);
                sIe[dl4 + 0][n] = __expf(-z4.x);
                sIe[dl4 + 1][n] = __expf(-z4.y);
                sIe[dl4 + 2][n] = __expf(-z4.z);
                sIe[dl4 + 3][n] = __expf(-z4.w);
            }
            __syncthreads();

            // ---- main loop over this phase's 32 dims, 4 chunks of 8 ----
            #pragma unroll 1
            for (int c = 0; c < 4; ++c) {
                #pragma unroll
                for (int k = 0; k < 8; ++k) {
                    const int dl = c * 8 + k;
                    const float2 Em2 = *reinterpret_cast<const float2*>(&sEm[dl][mi]);
                    const float2 Im2 = *reinterpret_cast<const float2*>(&sIm[dl][mi]);
                    const float2 Ee0 = *reinterpret_cast<const float2*>(&sEe[dl][ni]);
                    const float2 Ee1 = *reinterpret_cast<const float2*>(&sEe[dl][ni + 2]);
                    const float2 Ie0 = *reinterpret_cast<const float2*>(&sIe[dl][ni]);
                    const float2 Ie1 = *reinterpret_cast<const float2*>(&sIe[dl][ni + 2]);
                    const float EmA[2] = {Em2.x, Em2.y};
                    const float ImA[2] = {Im2.x, Im2.y};
                    const float EeA[4] = {Ee0.x, Ee0.y, Ee1.x, Ee1.y};
                    const float IeA[4] = {Ie0.x, Ie0.y, Ie1.x, Ie1.y};
                    #pragma unroll
                    for (int i = 0; i < 2; ++i) {
                        #pragma unroll
                        for (int jj = 0; jj < 4; ++jj) {
                            const float w = fmaf(fminf(EmA[i], EeA[jj]),
                                                 fminf(ImA[i], IeA[jj]), 1.0f);
                            p[i][jj] *= __log2f(w);    // raw v_log_f32
                        }
                    }
                }
                const float2 rc = *reinterpret_cast<const float2*>(&sRc[c][mi]);
                #pragma unroll
                for (int jj = 0; jj < 4; ++jj) { p[0][jj] *= rc.x; p[1][jj] *= rc.y; }
            }
            __syncthreads();   // LDS reuse: next phase/tile overwrites
        }

        // ---- store this tile ----
        #pragma unroll
        for (int i = 0; i < 2; ++i) {
            const int m = m0 + mi + i;
            if (m >= M) continue;
            const int n = n0 + ni;
            if (n + 4 <= N) {
                *reinterpret_cast<float4*>(&out[(size_t)m * N + n]) =
                    make_float4(p[i][0], p[i][1], p[i][2], p[i][3]);
            } else {
                #pragma unroll
                for (int jj = 0; jj < 4; ++jj)
                    if (n + jj < N) out[(size_t)m * N + n + jj] = p[i][jj];
            }
        }
    }
}

extern "C" void kernel_launch(void* const* d_in, const int* in_sizes, int n_in,
                              void* d_out, int out_size, void* d_ws, size_t ws_size,
                              hipStream_t stream) {
    const float* men = (const float*)d_in[0];
    const float* en  = (const float*)d_in[1];
    float* out = (float*)d_out;
    const int M = in_sizes[0] / 128;          // 256
    const int N = in_sizes[1] / 128;          // 20000
    const int ntl = (N + BN - 1) / BN;        // 313 n-tiles
    const int jst = (ntl + 1) / 2;            // 157 -> 2 tiles/block, balanced
    dim3 grid(jst, (M + BM - 1) / BM);        // 157 x 8 = 1256 blocks, ~4.9/CU
    ivr_kernel<<<grid, dim3(256), 0, stream>>>(men, en, out, M, N, ntl, jst);
}